// Round 6
// baseline (450.722 us; speedup 1.0000x reference)
//
#include <hip/hip_runtime.h>
#include <math.h>

// Problem constants (reference: VOCAB=10000, HID=256, B=64, T=64)
#define VOCABN 10000
#define HIDN   256
#define GATES  1024   // 4*HID
#define BN     64
#define TN     64
#define BT     4096   // B*T
#define NCT    625    // vocab col-tiles of 16 (10000 = 625*16 exactly)

// k_plstm row-sharded geometry (R4): 64 blocks x 1 batch row
#define HPITCH 264    // h LDS row pitch (bf16 elems) — breaks bank aliasing
#define HBUFE  4224   // 16 rows * 264 = one h buffer, u16 elems
#define WLDS_B 131072 // 128 KB LDS-resident W_h (8 waves x 16 frags x 1 KB)
#define SMEMSZ (WLDS_B + 2 * HBUFE * 2)   // 147968 B

typedef unsigned int       u32;
typedef unsigned short     u16;
typedef unsigned long long u64;
typedef float v4f __attribute__((ext_vector_type(4)));
typedef short v8s __attribute__((ext_vector_type(8)));

__device__ __forceinline__ float bf2f(u16 u) {
    return __uint_as_float(((u32)u) << 16);
}
__device__ __forceinline__ u16 f2bf(float f) {          // round-to-nearest-even
    u32 u = __float_as_uint(f);
    u += 0x7FFFu + ((u >> 16) & 1u);
    return (u16)(u >> 16);
}
// rcp-based (v_rcp_f32, ~1ulp): error ~1e-7, negligible vs bf16 h rounding.
__device__ __forceinline__ float fast_sigmoid(float x) {
    return __builtin_amdgcn_rcpf(1.0f + __expf(-x));
}
__device__ __forceinline__ float fast_tanh(float x) {
    float e = __expf(-2.0f * fabsf(x));
    float t = (1.0f - e) * __builtin_amdgcn_rcpf(1.0f + e);
    return copysignf(t, x);
}

// ---------------------------------------------------------------------------
// fp32 [HIDN][ncols] tile c -> bf16 MFMA B-fragment layout [c][8 q][64 l][8].
// Fragment (c,q), lane l holds B[k = q*32 + (l>>4)*8 + j][n = c*16 + (l&15)].
// ---------------------------------------------------------------------------
__device__ __forceinline__ void wfrag_dev(
    const float* __restrict__ src, u16* __restrict__ dst, int ncols, int c,
    int t, u16 lt[HIDN][16])
{
    const float* s = src + (size_t)t * ncols + c * 16;
    #pragma unroll
    for (int j4 = 0; j4 < 4; ++j4) {
        float4 v = *(const float4*)(s + j4 * 4);
        lt[t][j4*4+0] = f2bf(v.x);
        lt[t][j4*4+1] = f2bf(v.y);
        lt[t][j4*4+2] = f2bf(v.z);
        lt[t][j4*4+3] = f2bf(v.w);
    }
    __syncthreads();
    #pragma unroll
    for (int h = 0; h < 2; ++h) {
        int f = t + h * 256;             // frag id = q*64 + l
        int q = f >> 6, l = f & 63;
        int m = l & 15, kb = q * 32 + ((l >> 4) & 3) * 8;
        u32 w[4];
        #pragma unroll
        for (int j = 0; j < 4; ++j)
            w[j] = (u32)lt[kb + 2*j][m] | ((u32)lt[kb + 2*j + 1][m] << 16);
        *(uint4*)(dst + (((size_t)c * 8 + q) * 64 + l) * 8) =
            make_uint4(w[0], w[1], w[2], w[3]);
    }
}

// ---------------------------------------------------------------------------
// wfrag for both W_lstm halves (128 blocks) — fallback-path prep.
// ---------------------------------------------------------------------------
__global__ __launch_bounds__(256) void k_wfrag2(
    const float* __restrict__ W_lstm,
    u16* __restrict__ Wxf, u16* __restrict__ Whf)
{
    __shared__ u16 lt[HIDN][16];
    const int bid = blockIdx.x;
    if (bid < 64)
        wfrag_dev(W_lstm, Wxf, GATES, bid, threadIdx.x, lt);
    else
        wfrag_dev(W_lstm + (size_t)HIDN * GATES, Whf, GATES, bid - 64,
                  threadIdx.x, lt);
}

// ---------------------------------------------------------------------------
// ALL THREE weight transforms in one launch (753 blocks) — wide-ws path.
// ---------------------------------------------------------------------------
__global__ __launch_bounds__(256) void k_wfrag3(
    const float* __restrict__ W_lstm,
    const float* __restrict__ W_dense,
    u16* __restrict__ Wxf, u16* __restrict__ Whf, u16* __restrict__ Wf)
{
    __shared__ u16 lt[HIDN][16];
    const int bid = blockIdx.x;
    if (bid < 64)
        wfrag_dev(W_lstm, Wxf, GATES, bid, threadIdx.x, lt);
    else if (bid < 128)
        wfrag_dev(W_lstm + (size_t)HIDN * GATES, Whf, GATES, bid - 64,
                  threadIdx.x, lt);
    else
        wfrag_dev(W_dense, Wf, VOCABN, bid - 128, threadIdx.x, lt);
}

// ---------------------------------------------------------------------------
// wfrag for W_dense (625 blocks) — fallback path, runs AFTER plstm (Wf
// aliases gx2 there).
// ---------------------------------------------------------------------------
__global__ __launch_bounds__(256) void k_wfrag(
    const float* __restrict__ src,   // [HIDN][ncols]
    u16*         __restrict__ dst,   // [nct][8][64][8]
    int ncols)
{
    __shared__ u16 lt[HIDN][16];
    wfrag_dev(src, dst, ncols, blockIdx.x, threadIdx.x, lt);
}

// ---------------------------------------------------------------------------
// Kernel 1 (MFMA, R3-verbatim — PASSED): gates_x packed bf16+permuted.
// 256 blocks = (t 0..63) x (rg 0..3). Output gx2 u64 layout:
//   [((t*4+rg)*4 + w')*64 + lane][slot = gg*4 + gm]
// where for gate col-tile c (= gm*16 + G, group G = c&15): w' = G>>2,
// gg = G&3. One u64 = 4 bf16 (rows kq*4+r, r=0..3). Bias folded in.
// ---------------------------------------------------------------------------
__global__ __launch_bounds__(256) void k_xgates(
    const int*   __restrict__ idx,   // [BT] = [B][T]
    const float* __restrict__ E,     // [VOCAB][HIDN]
    const u16*   __restrict__ Wxf,   // [64][8][64][8]
    const float* __restrict__ bl,    // [GATES]
    u64*         __restrict__ gx2)   // [64*4*4*64*16] u64 (8 MB)
{
    const int bid = blockIdx.x;
    const int t   = bid >> 2, rg = bid & 3;
    const int tid = threadIdx.x;
    const int w   = tid >> 6, lane = tid & 63;
    const int m   = lane & 15, quad = lane >> 4;

    v8s a[8];
    {
        const float* e = E + (size_t)idx[(rg * 16 + m) * TN + t] * HIDN
                         + quad * 8;
        #pragma unroll
        for (int q = 0; q < 8; ++q) {
            float4 x0 = *(const float4*)(e + q * 32);
            float4 x1 = *(const float4*)(e + q * 32 + 4);
            uint4 t4 = make_uint4(
                (u32)f2bf(x0.x) | ((u32)f2bf(x0.y) << 16),
                (u32)f2bf(x0.z) | ((u32)f2bf(x0.w) << 16),
                (u32)f2bf(x1.x) | ((u32)f2bf(x1.y) << 16),
                (u32)f2bf(x1.z) | ((u32)f2bf(x1.w) << 16));
            a[q] = *(v8s*)&t4;
        }
    }

    for (int i = 0; i < 16; ++i) {
        const int c = 4 * i + w;          // col-tile, c%4 == w
        v4f acc = {0.f, 0.f, 0.f, 0.f};
        #pragma unroll
        for (int q = 0; q < 8; ++q) {
            v8s b = *(const v8s*)(Wxf + (((size_t)c * 8 + q) * 64 + lane) * 8);
            acc = __builtin_amdgcn_mfma_f32_16x16x32_bf16(a[q], b, acc, 0, 0, 0);
        }
        const float bv = bl[c * 16 + m];
        u32 lo = (u32)f2bf(acc[0] + bv) | ((u32)f2bf(acc[1] + bv) << 16);
        u32 hi = (u32)f2bf(acc[2] + bv) | ((u32)f2bf(acc[3] + bv) << 16);
        u64 pk = (u64)lo | ((u64)hi << 32);
        const size_t di =
            ((((size_t)t * 4 + rg) * 4 + ((c & 15) >> 2)) * 64 + lane) * 16
            + (c & 3) * 4 + (c >> 4);
        gx2[di] = pk;
    }
}

// ---------------------------------------------------------------------------
// Kernel 2: ROW-SHARDED zero-exchange persistent LSTM (R4, resubmitted —
// R5's bench was an infra failure, kernel never ran).
//
// R3 post-mortem: with 4 blocks x 16 rows, the cell phase (8 cells/lane x
// ~10 transcendentals) was a serial ~1.8us VALU wall per step on 4 CUs
// (per-CU VALUBusy ~50%). Batch rows are INDEPENDENT sequences (h enters
// gates only as h@W_h per row), so shard ROWS not units:
//
// 64 blocks x 512 thr (8 waves, 2/SIMD), block = ONE batch row, all 256
// units, zero inter-block traffic. MFMA structure is R3-verbatim (PASSED):
// wave w owns unit-groups gA=2w, gB=2w+1; 48 W frags in regs + 16 in LDS.
// The 16-row M-tile now carries 15 garbage rows (16x redundant MFMA — MFMA
// was 23%/CU busy, per-CU MFMA work unchanged, rows can't cross-contaminate;
// h buffers zero-initialized so garbage rows stay 0).
//
// Block bid: rg = bid>>4 (gx2 row-group), rv = bid&15 (tile row),
// kqv = rv>>2 (valid quad), rr = bid&3 (valid acc element, block-uniform ->
// compile-time-selected via uniform branch, no dynamic v4f indexing).
// Only the kqv quad loads gb / runs cells: 2 cells/lane (units uA, uB).
// Per-step critical path: a-frag ds_read + 64 MFMA/wave + 2-cell VALU +
// one lgkmcnt(0)+s_barrier.
// ---------------------------------------------------------------------------
__global__ __launch_bounds__(512, 2) void k_plstm(
    const u16*   __restrict__ Whf,   // [64 ct][8 q][64 l][8] h-part frags
    const u64*   __restrict__ gx2,   // packed x-gates (see k_xgates)
    u16*         __restrict__ Hb)    // [BT][HIDN] bf16 output
{
    extern __shared__ char smem[];
    u16* WgL   = (u16*)smem;                 // [8 w][2 gm2][8 q][64 l][8]
    u16* hbufu = (u16*)(smem + WLDS_B);      // [2][16][HPITCH] u16

    const int tid  = threadIdx.x;
    const int bid  = blockIdx.x;             // 0..63: global batch row
    const int rg   = bid >> 4;               // gx2 row-group
    const int rv   = bid & 15;               // row within the 16-row tile
    const int kqv  = rv >> 2;                // quad holding this row's gates
    const int rr   = rv & 3;                 // acc element (block-uniform)
    const int w    = tid >> 6;               // 0..7
    const int lane = tid & 63;
    const int m    = lane & 15, kq = lane >> 4;
    const int uA   = 32 * w + m;             // group A unit of this lane
    const int uB   = uA + 16;                // group B unit
    const bool val = (kq == kqv);

    // ---- prologue: W into registers + LDS (R3-verbatim) ----
    const int gA = 2 * w, gB = 2 * w + 1;
    v8s wrA[4][8], wrB[2][8];
    #pragma unroll
    for (int gm = 0; gm < 4; ++gm)
        #pragma unroll
        for (int q = 0; q < 8; ++q)
            wrA[gm][q] = *(const v8s*)(
                Whf + (((size_t)(gm * 16 + gA) * 8 + q) * 64 + lane) * 8);
    #pragma unroll
    for (int gm = 0; gm < 2; ++gm)
        #pragma unroll
        for (int q = 0; q < 8; ++q)
            wrB[gm][q] = *(const v8s*)(
                Whf + (((size_t)(gm * 16 + gB) * 8 + q) * 64 + lane) * 8);
    #pragma unroll
    for (int gm2 = 0; gm2 < 2; ++gm2)
        #pragma unroll
        for (int q = 0; q < 8; ++q)
            *(uint4*)(WgL + (((w * 2 + gm2) * 8 + q) * 64 + lane) * 8) =
                *(const uint4*)(
                    Whf + (((size_t)((gm2 + 2) * 16 + gB) * 8 + q) * 64
                           + lane) * 8);

    {   // zero BOTH h buffers (garbage rows stay 0 forever; t=0 h(-1)=0)
        u32* hz = (u32*)hbufu;
        for (int i = tid; i < HBUFE; i += 512) hz[i] = 0u;
    }

    float cA = 0.0f, cB = 0.0f;
    __syncthreads();

    const int sbase = 8 * (w & 1);           // gx2 slot base for this wave

    // cell pair for compile-time acc element R (only the kqv quad runs this)
    #define CPAIR(R)                                                          \
    {                                                                         \
        float xiA = bf2f((u16)(gb[0] >> (16 * (R))));                         \
        float xjA = bf2f((u16)(gb[1] >> (16 * (R))));                         \
        float xfA = bf2f((u16)(gb[2] >> (16 * (R))));                         \
        float xoA = bf2f((u16)(gb[3] >> (16 * (R))));                         \
        float igA = fast_sigmoid(eA0[R] + xiA);                               \
        float jtA = fast_tanh   (eA1[R] + xjA);                               \
        float fgA = fast_sigmoid(eA2[R] + xfA + 1.0f);                        \
        float ogA = fast_sigmoid(eA3[R] + xoA);                               \
        cA = fgA * cA + igA * jtA;                                            \
        u16 hA = f2bf(ogA * fast_tanh(cA));                                   \
        float xiB = bf2f((u16)(gb[4] >> (16 * (R))));                         \
        float xjB = bf2f((u16)(gb[5] >> (16 * (R))));                         \
        float xfB = bf2f((u16)(gb[6] >> (16 * (R))));                         \
        float xoB = bf2f((u16)(gb[7] >> (16 * (R))));                         \
        float igB = fast_sigmoid(eB0[R] + xiB);                               \
        float jtB = fast_tanh   (eB1[R] + xjB);                               \
        float fgB = fast_sigmoid(eB2[R] + xfB + 1.0f);                        \
        float ogB = fast_sigmoid(eB3[R] + xoB);                               \
        cB = fgB * cB + igB * jtB;                                            \
        u16 hB = f2bf(ogB * fast_tanh(cB));                                   \
        hwr[rv * HPITCH + uA] = hA;                                           \
        hwr[rv * HPITCH + uB] = hB;                                           \
        Hb[((size_t)bid * TN + t) * HIDN + uA] = hA;                          \
        Hb[((size_t)bid * TN + t) * HIDN + uB] = hB;                          \
    }

    for (int t = 0; t < TN; ++t) {
        const u16* hrd = hbufu + (t & 1) * HBUFE;
        u16*       hwr = hbufu + ((t + 1) & 1) * HBUFE;

        // x-gates for THIS step (valid quad only): 8 u64/lane, latency
        // covered by the MFMA phase
        u64 gb[8];
        if (val) {
            const u64* gp = gx2
                + ((((size_t)t * 4 + rg) * 4 + (w >> 1)) * 64
                   + kqv * 16 + m) * 16 + sbase;
            #pragma unroll
            for (int j = 0; j < 8; ++j) gb[j] = gp[j];
        }

        v4f eA0 = {0.f,0.f,0.f,0.f}, eA1 = {0.f,0.f,0.f,0.f};
        v4f eA2 = {0.f,0.f,0.f,0.f}, eA3 = {0.f,0.f,0.f,0.f};
        v4f eB0 = {0.f,0.f,0.f,0.f}, eB1 = {0.f,0.f,0.f,0.f};
        v4f eB2 = {0.f,0.f,0.f,0.f}, eB3 = {0.f,0.f,0.f,0.f};

        const u16* abase = hrd + m * HPITCH + kq * 8;
        #pragma unroll
        for (int q = 0; q < 8; ++q) {
            v8s aq = *(const v8s*)(abase + q * 32);
            v8s b2 = *(const v8s*)(WgL + (((w * 2 + 0) * 8 + q) * 64 + lane) * 8);
            v8s b3 = *(const v8s*)(WgL + (((w * 2 + 1) * 8 + q) * 64 + lane) * 8);
            eB2 = __builtin_amdgcn_mfma_f32_16x16x32_bf16(aq, b2, eB2, 0, 0, 0);
            eB3 = __builtin_amdgcn_mfma_f32_16x16x32_bf16(aq, b3, eB3, 0, 0, 0);
            eA0 = __builtin_amdgcn_mfma_f32_16x16x32_bf16(aq, wrA[0][q], eA0, 0, 0, 0);
            eA1 = __builtin_amdgcn_mfma_f32_16x16x32_bf16(aq, wrA[1][q], eA1, 0, 0, 0);
            eA2 = __builtin_amdgcn_mfma_f32_16x16x32_bf16(aq, wrA[2][q], eA2, 0, 0, 0);
            eA3 = __builtin_amdgcn_mfma_f32_16x16x32_bf16(aq, wrA[3][q], eA3, 0, 0, 0);
            eB0 = __builtin_amdgcn_mfma_f32_16x16x32_bf16(aq, wrB[0][q], eB0, 0, 0, 0);
            eB1 = __builtin_amdgcn_mfma_f32_16x16x32_bf16(aq, wrB[1][q], eB1, 0, 0, 0);
        }

        // ---- cells: only the valid quad, only acc element rr ----
        if (val) {
            if      (rr == 0) CPAIR(0)
            else if (rr == 1) CPAIR(1)
            else if (rr == 2) CPAIR(2)
            else              CPAIR(3)
        }

        // light barrier: drain LDS ops only (Hb stores / gx loads stay in
        // flight across steps). Same pattern as R3 (HW-validated).
        asm volatile("s_waitcnt lgkmcnt(0)" ::: "memory");
        __builtin_amdgcn_s_barrier();
    }
    #undef CPAIR
}

// ---------------------------------------------------------------------------
// Kernel 3 (MFMA dense, 8-way vocab split — R14 verbatim): 512 blocks =
// 64 row-groups(64 rows, 4 register-resident a-frag row-tiles) x 8 vocab
// eighths (~640 KB Wf each, L2-resident per XCD under round-robin %8).
// ---------------------------------------------------------------------------
__global__ __launch_bounds__(256, 1) void k_dense(
    const u16*   __restrict__ Hb,    // [BT][HIDN] bf16
    const u16*   __restrict__ Wf,    // [625][8][64][8]
    const float* __restrict__ bd,    // [VOCAB]
    float*       __restrict__ S)     // [8][BT] partial sumexp
{
    __shared__ float Sl[64];
    const int bid = blockIdx.x;
    const int hv  = bid & 7;                    // vocab eighth (XCD-aligned)
    const int rg  = bid >> 3;                   // 0..63
    const int r0  = rg * 64;
    const int tid = threadIdx.x;
    const int w   = tid >> 6, lane = tid & 63;
    const int m   = lane & 15, kq = lane >> 4;

    if (tid < 64) Sl[tid] = 0.0f;

    v8s a[4][8];
    #pragma unroll
    for (int rt = 0; rt < 4; ++rt) {
        const u16* hrow = Hb + (size_t)(r0 + rt * 16 + m) * HIDN + kq * 8;
        #pragma unroll
        for (int q = 0; q < 8; ++q)
            a[rt][q] = *(const v8s*)(hrow + q * 32);
    }
    __syncthreads();

    float s[4][4] = {{0.f,0.f,0.f,0.f},{0.f,0.f,0.f,0.f},
                     {0.f,0.f,0.f,0.f},{0.f,0.f,0.f,0.f}};
    const int cbeg = (hv * NCT) >> 3;
    const int cend = ((hv + 1) * NCT) >> 3;
    for (int c = cbeg + w; c < cend; c += 4) {
        v4f acc[4] = {{0.f,0.f,0.f,0.f},{0.f,0.f,0.f,0.f},
                      {0.f,0.f,0.f,0.f},{0.f,0.f,0.f,0.f}};
        #pragma unroll
        for (int q = 0; q < 8; ++q) {
            v8s bq = *(const v8s*)(Wf + (((size_t)c * 8 + q) * 64 + lane) * 8);
            #pragma unroll
            for (int rt = 0; rt < 4; ++rt)
                acc[rt] = __builtin_amdgcn_mfma_f32_16x16x32_bf16(
                              a[rt][q], bq, acc[rt], 0, 0, 0);
        }
        const float bv = bd[c * 16 + m];
        #pragma unroll
        for (int rt = 0; rt < 4; ++rt)
            #pragma unroll
            for (int r = 0; r < 4; ++r)
                s[rt][r] += __expf(acc[rt][r] + bv);
    }

    #pragma unroll
    for (int rt = 0; rt < 4; ++rt)
        #pragma unroll
        for (int r = 0; r < 4; ++r)
            atomicAdd(&Sl[rt * 16 + kq * 4 + r], s[rt][r]);
    __syncthreads();
    if (tid < 64) S[(size_t)hv * BT + r0 + tid] = Sl[tid];
}

// ---------------------------------------------------------------------------
// Kernel 4 (target + final fused — R14 verbatim): per row, dot h with the
// target's W column (32 thr/row), then ppl = exp(log(sum S) - logit).
// ---------------------------------------------------------------------------
__global__ __launch_bounds__(256) void k_target(
    const u16*   __restrict__ Hb,
    const u16*   __restrict__ Wf,
    const float* __restrict__ bd,
    const int*   __restrict__ tgt,
    const float* __restrict__ S,     // [8][BT]
    float*       __restrict__ out)   // [BT]
{
    const int tid = threadIdx.x;
    const int row = blockIdx.x * 8 + (tid >> 5);
    const int t   = tid & 31;
    const int q   = t >> 2, lq = t & 3;
    const int v   = tgt[row];
    const int c   = v >> 4, vm = v & 15;
    const int kb  = q * 32 + lq * 8;

    v8s h  = *(const v8s*)(Hb + (size_t)row * HIDN + kb);
    v8s wv = *(const v8s*)(Wf + (((size_t)c * 8 + q) * 64 + lq * 16 + vm) * 8);
    float acc = 0.0f;
    #pragma unroll
    for (int j = 0; j < 8; ++j)
        acc = fmaf(bf2f((u16)h[j]), bf2f((u16)wv[j]), acc);
    #pragma unroll
    for (int off = 16; off >= 1; off >>= 1)
        acc += __shfl_down(acc, off, 32);
    if (t == 0) {
        float tlv = acc + bd[v];
        float sum = 0.0f;
        #pragma unroll
        for (int p = 0; p < 8; ++p) sum += S[(size_t)p * BT + row];
        out[row] = __expf(__logf(sum) - tlv);
    }
}

// ---------------------------------------------------------------------------
extern "C" void kernel_launch(void* const* d_in, const int* in_sizes, int n_in,
                              void* d_out, int out_size, void* d_ws, size_t ws_size,
                              hipStream_t stream) {
    const int*   input   = (const int*)  d_in[0];   // [B,T]
    const int*   targets = (const int*)  d_in[1];   // [B,T]
    const float* E       = (const float*)d_in[2];   // [VOCAB,HID]
    const float* W_lstm  = (const float*)d_in[3];   // [2H,4H]
    const float* b_lstm  = (const float*)d_in[4];   // [4H]
    const float* W_dense = (const float*)d_in[5];   // [HID,VOCAB]
    const float* b_dense = (const float*)d_in[6];   // [VOCAB]
    float* out = (float*)d_out;                     // [B,T] perplexity

    static bool attr_done = false;
    if (!attr_done) {
        hipFuncSetAttribute((const void*)k_plstm,
                            hipFuncAttributeMaxDynamicSharedMemorySize,
                            SMEMSZ);
        attr_done = true;
    }

    char* ws = (char*)d_ws;
    const bool wide = (ws_size >= ((size_t)25 << 20));

    if (wide) {
        // 5-node layout:
        //  [0,8M): gx2 | [16M,21.12M): Wf | [21.25M,23.25M): Hb
        //  [23.25M,+512K): Whf | [23.75M,+512K): Wxf
        //  [24.25M+128K,+128K): S
        u64*   gx2 = (u64*)ws;
        u16*   Wf  = (u16*)(ws + ((size_t)16 << 20));
        u16*   Hb  = (u16*)(ws + ((size_t)21 << 20) + ((size_t)256 << 10));
        u16*   Whf = (u16*)(ws + ((size_t)23 << 20) + ((size_t)256 << 10));
        u16*   Wxf = (u16*)(ws + ((size_t)23 << 20) + ((size_t)768 << 10));
        float* S   = (float*)(ws + ((size_t)24 << 20) + ((size_t)384 << 10));

        k_wfrag3<<<753,     256, 0, stream>>>(W_lstm, W_dense, Wxf, Whf, Wf);
        k_xgates<<<BT / 16, 256, 0, stream>>>(input, E, Wxf, b_lstm, gx2);
        k_plstm <<<64,      512, SMEMSZ, stream>>>(Whf, gx2, Hb);
        k_dense <<<512,     256, 0, stream>>>(Hb, Wf, b_dense, S);
        k_target<<<BT / 8,  256, 0, stream>>>(Hb, Wf, b_dense, targets, S, out);
    } else {
        // 6-node fallback (Wf aliases gx2 after plstm).
        //  [0,8M): gx2/Wf | [16M,18M): Hb | [18M,+512K): Whf
        //  [18.5M,+512K): Wxf | [19M+128K,+128K): S
        u64*   gx2 = (u64*)ws;
        u16*   Wf  = (u16*)ws;
        u16*   Hb  = (u16*)(ws + ((size_t)16 << 20));
        u16*   Whf = (u16*)(ws + ((size_t)18 << 20));
        u16*   Wxf = (u16*)(ws + ((size_t)18 << 20) + ((size_t)512 << 10));
        float* S   = (float*)(ws + ((size_t)19 << 20) + ((size_t)128 << 10));

        k_wfrag2<<<128,     256, 0, stream>>>(W_lstm, Wxf, Whf);
        k_xgates<<<BT / 16, 256, 0, stream>>>(input, E, Wxf, b_lstm, gx2);
        k_plstm <<<64,      512, SMEMSZ, stream>>>(Whf, gx2, Hb);
        k_wfrag <<<NCT,     256, 0, stream>>>(W_dense, Wf, VOCABN);
        k_dense <<<512,     256, 0, stream>>>(Hb, Wf, b_dense, S);
        k_target<<<BT / 8,  256, 0, stream>>>(Hb, Wf, b_dense, targets, S, out);
    }
}